// Round 2
// baseline (734.978 us; speedup 1.0000x reference)
//
#include <hip/hip_runtime.h>
#include <hip/hip_fp16.h>

// Problem constants (fixed by the reference)
#define BB     16
#define CIN    64
#define NN     40962
#define COUT   32
#define NEWN   (4*NN - 6)            // 163842
#define GROUPS_PER_B ((NEWN + 31)/32) // 5121
#define NGROUPS (BB * GROUPS_PER_B)   // 81936

typedef _Float16 f16x8  __attribute__((ext_vector_type(8)));
typedef float    f32x16 __attribute__((ext_vector_type(16)));
typedef _Float16 h2     __attribute__((ext_vector_type(2)));

__device__ __forceinline__ int pk_add_h2(int a, int b) {
  h2 r = __builtin_bit_cast(h2, a) + __builtin_bit_cast(h2, b);
  return __builtin_bit_cast(int, r);
}
__device__ __forceinline__ int pack2(float lo, float hi) {
  h2 r; r.x = (_Float16)lo; r.y = (_Float16)hi;
  return __builtin_bit_cast(int, r);
}

// ---------------- transpose: x (B,64,N) f32  ->  xT (B,N,64) f16 ----------------
// float2 global reads (rows are only 8B-aligned: NN%4==2), int4 (8x f16) writes.
__global__ __launch_bounds__(256) void k_transpose(const float* __restrict__ x,
                                                   __half* __restrict__ xT) {
  __shared__ float tile[64][65];
  const int b   = blockIdx.y;
  const int n0  = blockIdx.x * 64;
  const int tid = threadIdx.x;
  const float* xb = x + (size_t)b * CIN * NN;

  const int cr8 = tid >> 5;      // 0..7
  const int nh  = tid & 31;      // 0..31 -> n = n0 + nh*2 (+0/1)
  if (n0 + 64 <= NN) {
#pragma unroll
    for (int p = 0; p < 8; ++p) {
      const int c = p * 8 + cr8;
      float2 v = *reinterpret_cast<const float2*>(xb + (size_t)c * NN + n0 + nh * 2);
      tile[c][nh * 2 + 0] = v.x;
      tile[c][nh * 2 + 1] = v.y;
    }
  } else {
#pragma unroll
    for (int p = 0; p < 8; ++p) {
      const int c = p * 8 + cr8;
      const int na = n0 + nh * 2, nb = na + 1;
      tile[c][nh * 2 + 0] = (na < NN) ? xb[(size_t)c * NN + na] : 0.f;
      tile[c][nh * 2 + 1] = (nb < NN) ? xb[(size_t)c * NN + nb] : 0.f;
    }
  }
  __syncthreads();

  __half* xTb = xT + (size_t)b * NN * CIN;
  const int nr = tid >> 3;   // 0..31
  const int ch = tid & 7;    // 0..7 -> c = ch*8 .. +7
#pragma unroll
  for (int p = 0; p < 2; ++p) {
    const int nl = p * 32 + nr;
    const int n  = n0 + nl;
    if (n < NN) {
      int4 v;
      v.x = pack2(tile[ch * 8 + 0][nl], tile[ch * 8 + 1][nl]);
      v.y = pack2(tile[ch * 8 + 2][nl], tile[ch * 8 + 3][nl]);
      v.z = pack2(tile[ch * 8 + 4][nl], tile[ch * 8 + 5][nl]);
      v.w = pack2(tile[ch * 8 + 6][nl], tile[ch * 8 + 7][nl]);
      *reinterpret_cast<int4*>(xTb + (size_t)n * CIN + ch * 8) = v;
    }
  }
}

// ---------------- MFMA compute: sparse-K=448(+8 bias) GEMM --------
// v3: A fragments in LDS (29.7 KB/block, shared by all 4 waves) instead of 116 VGPRs.
//     -> VGPR < 128 -> 4 waves/SIMD (launch_bounds(256,4)), grid 2048 blocks.
//     No software pipeline (v2's double GD spilled: VGPR=124 + 68MB scratch writes).
//     Pure-top groups (wave-uniform g*32+31 < NN) skip the duplicate col1 gather.
//     XCD-chunked block swizzle: each XCD works a contiguous 1024-gid window (~1 b-slice).
__global__ __launch_bounds__(256, 4) void k_upconv_mfma(
    const __half* __restrict__ xT, const float* __restrict__ W,
    const float* __restrict__ bias, const int* __restrict__ top,
    const int* __restrict__ down, float* __restrict__ out) {
  __shared__ int4 Aflds[29][64];   // [step][lane] 16B fragments
  const int tid  = threadIdx.x;
  const int lane = tid & 63;
  const int co   = lane & 31;        // A row (M) / output slot (N)
  const int h    = lane >> 5;        // k-half

  // ---- cooperative build of A fragments in LDS (all 256 threads) ----
  for (int p = tid; p < 28 * 64; p += 256) {
    const int s  = p >> 6, l = p & 63;
    const int lc = l & 31, lh = l >> 5;
    const int t  = s >> 2;
    const int c0 = 16 * (s & 3) + 8 * lh;
    const float* wr = W + (lc * 7 + t) * 64 + c0;
    float4 wa = *(const float4*)wr;
    float4 wb = *(const float4*)(wr + 4);
    int4 v;
    v.x = pack2(0.5f * wa.x, 0.5f * wa.y);
    v.y = pack2(0.5f * wa.z, 0.5f * wa.w);
    v.z = pack2(0.5f * wb.x, 0.5f * wb.y);
    v.w = pack2(0.5f * wb.z, 0.5f * wb.w);
    Aflds[s][l] = v;
  }
  if (tid < 64) {
    int4 ab = {0, 0, 0, 0};
    if ((tid >> 5) == 0) {
      const int lc = tid & 31;
      float bv[8];
#pragma unroll
      for (int tau = 0; tau < 7; ++tau) bv[tau] = 0.5f * bias[lc * 7 + tau];
      bv[7] = 0.f;
      ab.x = pack2(bv[0], bv[1]);
      ab.y = pack2(bv[2], bv[3]);
      ab.z = pack2(bv[4], bv[5]);
      ab.w = pack2(bv[6], bv[7]);
    }
    Aflds[28][tid] = ab;
  }
  __syncthreads();

  // ---- XCD-chunked swizzle (gridDim.x must be a multiple of 8; it is 2048) ----
  const int nblocks = gridDim.x;
  const int sbid = (blockIdx.x & 7) * (nblocks >> 3) + (blockIdx.x >> 3);
  const int gwave  = sbid * (blockDim.x >> 6) + (tid >> 6);
  const int nwaves = nblocks * (blockDim.x >> 6);

  for (int gid = gwave; gid < NGROUPS; gid += nwaves) {
    const int b = gid / GROUPS_PER_B;
    const int g = gid - b * GROUPS_PER_B;
    const int k = g * 32 + co;
    const __half* xTb = xT + (size_t)b * NN * CIN;

    int4 col0[4], col1[4];
    int t0, t1;
    bool valid = true;

    if (g * 32 + 31 < NN) {
      // pure-top group: j2 == j1 for every lane -> one gather, col1 = col0
      const int j1 = top[k];
      t0 = j1 / NN; t1 = t0;
      const int n0 = j1 - t0 * NN;
      const int4* base0 = (const int4*)(xTb + (size_t)n0 * CIN);
#pragma unroll
      for (int q = 0; q < 4; ++q) col0[q] = base0[2 * q + h];
#pragma unroll
      for (int q = 0; q < 4; ++q) col1[q] = col0[q];
    } else {
      valid = (k < NEWN);
      int j1 = 0, j2 = 0;
      if (valid) {
        if (k < NN) { j1 = top[k]; j2 = j1; }
        else {
          int2 jj = *reinterpret_cast<const int2*>(down + 2 * (k - NN));
          j1 = jj.x; j2 = jj.y;
        }
      }
      t0 = j1 / NN; const int n0 = j1 - t0 * NN;
      t1 = j2 / NN; const int n1 = j2 - t1 * NN;
      const int4* base0 = (const int4*)(xTb + (size_t)n0 * CIN);
      const int4* base1 = (const int4*)(xTb + (size_t)n1 * CIN);
#pragma unroll
      for (int q = 0; q < 4; ++q) col0[q] = base0[2 * q + h];
#pragma unroll
      for (int q = 0; q < 4; ++q) col1[q] = base1[2 * q + h];
    }

    f32x16 acc;
#pragma unroll
    for (int i = 0; i < 16; ++i) acc[i] = 0.f;

    // ---- main K loop: 28 data steps, A fragment re-read from LDS each step ----
#pragma unroll
    for (int s = 0; s < 28; ++s) {
      const int t = s >> 2, q = s & 3;
      const bool m0 = (t0 == t), m1 = (t1 == t);
      int4 bb;
      bb.x = pk_add_h2(m0 ? col0[q].x : 0, m1 ? col1[q].x : 0);
      bb.y = pk_add_h2(m0 ? col0[q].y : 0, m1 ? col1[q].y : 0);
      bb.z = pk_add_h2(m0 ? col0[q].z : 0, m1 ? col1[q].z : 0);
      bb.w = pk_add_h2(m0 ? col0[q].w : 0, m1 ? col1[q].w : 0);
      const int4 a_s = Aflds[s][lane];
      acc = __builtin_amdgcn_mfma_f32_32x32x16_f16(
          __builtin_bit_cast(f16x8, a_s), __builtin_bit_cast(f16x8, bb), acc, 0, 0, 0);
    }

    // ---- bias step: selector chunk on B ----
    {
      int4 bsel = {0, 0, 0, 0};
      if (h == 0) {
        bsel.x = pack2((float)((t0 == 0) + (t1 == 0)), (float)((t0 == 1) + (t1 == 1)));
        bsel.y = pack2((float)((t0 == 2) + (t1 == 2)), (float)((t0 == 3) + (t1 == 3)));
        bsel.z = pack2((float)((t0 == 4) + (t1 == 4)), (float)((t0 == 5) + (t1 == 5)));
        bsel.w = pack2((float)((t0 == 6) + (t1 == 6)), 0.f);
      }
      const int4 a28 = Aflds[28][lane];
      acc = __builtin_amdgcn_mfma_f32_32x32x16_f16(
          __builtin_bit_cast(f16x8, a28), __builtin_bit_cast(f16x8, bsel), acc, 0, 0, 0);
    }

    // ---- store: D[co_row][slot], slot = lane&31 -> coalesced 128B segments ----
    // Nontemporal: 335MB streaming writes must not evict xT from L2/L3.
    if (valid) {
      float* ob = out + (size_t)b * COUT * NEWN + k;
#pragma unroll
      for (int r = 0; r < 16; ++r) {
        const int corow = (r & 3) + 8 * (r >> 2) + 4 * h;
        __builtin_nontemporal_store(acc[r], ob + (size_t)corow * NEWN);
      }
    }
  }
}

// ---------------- fallback (workspace too small): fp32, strided x reads ----------------
#define WPB 68
#define TPB (32*WPB + 4)

__global__ __launch_bounds__(256) void k_upconv_f32(
    const float* __restrict__ x, const float* __restrict__ W,
    const float* __restrict__ bias, const int* __restrict__ top,
    const int* __restrict__ down, float* __restrict__ out) {
  __shared__ float wl[7 * TPB];
  __shared__ float bl[224];
  const int tid = threadIdx.x;
  for (int p = tid; p < 224 * 64; p += 256) {
    int o = p >> 6, c = p & 63;
    wl[(o % 7) * TPB + (o / 7) * WPB + c] = W[p];
  }
  if (tid < 224) bl[tid] = bias[tid];
  __syncthreads();

  const int b = blockIdx.y;
  const int k = blockIdx.x * 256 + tid;

  int nit = 0, t0 = 0, t1 = 0, n0 = 0, n1 = 0;
  if (k < NEWN) {
    if (k < NN) {
      int j = top[k];
      t0 = j / NN; n0 = j - t0 * NN; nit = 1;
    } else {
      int kk = k - NN;
      int j1 = down[2 * kk], j2 = down[2 * kk + 1];
      t0 = j1 / NN; n0 = j1 - t0 * NN;
      t1 = j2 / NN; n1 = j2 - t1 * NN;
      nit = 2;
    }
  }

  float acc[32];
#pragma unroll
  for (int i = 0; i < 32; ++i) acc[i] = 0.f;

  for (int it = 0; it < nit; ++it) {
    const int t = it ? t1 : t0;
    const int n = it ? n1 : n0;
    const float* col = x + (size_t)b * CIN * NN + n;
    const int base = t * TPB;
#pragma unroll
    for (int ch = 0; ch < 8; ++ch) {
      float xv[8];
#pragma unroll
      for (int q = 0; q < 8; ++q) xv[q] = col[(size_t)(ch * 8 + q) * NN];
#pragma unroll
      for (int co = 0; co < 32; ++co) {
        float a = acc[co];
        const float* wr = &wl[base + co * WPB + ch * 8];
        float4 w0 = *(const float4*)(wr);
        float4 w1 = *(const float4*)(wr + 4);
        a += w0.x * xv[0]; a += w0.y * xv[1]; a += w0.z * xv[2]; a += w0.w * xv[3];
        a += w1.x * xv[4]; a += w1.y * xv[5]; a += w1.z * xv[6]; a += w1.w * xv[7];
        acc[co] = a;
      }
    }
  }

  if (k < NEWN) {
    float* ob = out + (size_t)b * COUT * NEWN + k;
    if (k < NN) {
#pragma unroll
      for (int co = 0; co < 32; ++co)
        ob[(size_t)co * NEWN] = acc[co] + bl[co * 7 + t0];
    } else {
#pragma unroll
      for (int co = 0; co < 32; ++co)
        ob[(size_t)co * NEWN] = 0.5f * (acc[co] + bl[co * 7 + t0] + bl[co * 7 + t1]);
    }
  }
}

extern "C" void kernel_launch(void* const* d_in, const int* in_sizes, int n_in,
                              void* d_out, int out_size, void* d_ws, size_t ws_size,
                              hipStream_t stream) {
  const float* x    = (const float*)d_in[0];
  const float* W    = (const float*)d_in[1];
  const float* bias = (const float*)d_in[2];
  const int*   top  = (const int*)d_in[3];
  const int*   down = (const int*)d_in[4];
  float* out = (float*)d_out;

  const size_t xT_bytes = (size_t)BB * NN * CIN * sizeof(__half);  // ~84 MB
  if (ws_size >= xT_bytes) {
    __half* xT = (__half*)d_ws;
    k_transpose<<<dim3((NN + 63) / 64, BB), 256, 0, stream>>>(x, xT);
    k_upconv_mfma<<<dim3(2048), 256, 0, stream>>>(xT, W, bias, top, down, out);
  } else {
    k_upconv_f32<<<dim3((NEWN + 255) / 256, BB), 256, 0, stream>>>(x, W, bias, top, down, out);
  }
}